// Round 12
// baseline (379.163 us; speedup 1.0000x reference)
//
#include <hip/hip_runtime.h>
#include <hip/hip_bf16.h>
#include <hip/hip_fp16.h>

#define D 128
#define EPB 4096      // edges per phase-A block (256 thr x 16)
#define NBMAX 784     // max coarse bins (ceil(100000/128)=782)
#define BCAP 2560     // per-coarse-bin capacity: Poisson(2048) + 11 sigma

typedef _Float16 half8 __attribute__((ext_vector_type(8)));
typedef _Float16 half4 __attribute__((ext_vector_type(4)));
typedef float f32x4 __attribute__((ext_vector_type(4)));
typedef float f32x8 __attribute__((ext_vector_type(8)));

// ============ W prep: WT[n][k] = (fp16) W[k][n], both weights ============

__global__ void k_prepW2(const float* __restrict__ W1, const float* __restrict__ W2,
                         _Float16* __restrict__ WT1, _Float16* __restrict__ WT2) {
    const int i = blockIdx.x * 256 + threadIdx.x;
    if (i < 2 * D * D) {
        const float* W = (i < D * D) ? W1 : W2;
        _Float16* WT   = (i < D * D) ? WT1 : WT2;
        const int j = (i < D * D) ? i : i - D * D;
        const int k = j >> 7, n = j & 127;
        WT[n * D + k] = (_Float16)W[j];
    }
}

// ============ GEMM body (A from global), fp16 out ============

template <typename AT>
__device__ __forceinline__ void gemm_body(int bid, const AT* __restrict__ A,
                                          const _Float16* __restrict__ WT,
                                          _Float16* __restrict__ Hout, int nrows) {
    const int wv   = threadIdx.x >> 6;
    const int lane = threadIdx.x & 63;
    const int l    = lane & 15;
    const int quad = lane >> 4;
    const int base = bid * 64 + wv * 16;
    int row = base + l;
    const bool valid = row < nrows;
    if (!valid) row = nrows - 1;

    half8 af[4];
    const AT* Ar = &A[(size_t)row * D + quad * 8];
    #pragma unroll
    for (int s = 0; s < 4; ++s) {
        if constexpr (sizeof(AT) == 4) {
            const float4 v0 = *(const float4*)(Ar + s * 32);
            const float4 v1 = *(const float4*)(Ar + s * 32 + 4);
            af[s][0] = (_Float16)v0.x; af[s][1] = (_Float16)v0.y;
            af[s][2] = (_Float16)v0.z; af[s][3] = (_Float16)v0.w;
            af[s][4] = (_Float16)v1.x; af[s][5] = (_Float16)v1.y;
            af[s][6] = (_Float16)v1.z; af[s][7] = (_Float16)v1.w;
        } else {
            af[s] = *(const half8*)(Ar + s * 32);
        }
    }

    f32x4 acc[8];
    #pragma unroll
    for (int t = 0; t < 8; ++t) acc[t] = (f32x4)0.0f;

    #pragma unroll
    for (int s = 0; s < 4; ++s) {
        #pragma unroll
        for (int t = 0; t < 8; ++t) {
            const half8 wf = *(const half8*)&WT[(size_t)(t * 16 + l) * D + s * 32 + quad * 8];
            acc[t] = __builtin_amdgcn_mfma_f32_16x16x32_f16(wf, af[s], acc[t], 0, 0, 0);
        }
    }

    if (valid) {
        _Float16* Or = &Hout[(size_t)row * D + quad * 4];
        #pragma unroll
        for (int t = 0; t < 8; ++t) {
            half4 o;
            o[0] = (_Float16)acc[t][0]; o[1] = (_Float16)acc[t][1];
            o[2] = (_Float16)acc[t][2]; o[3] = (_Float16)acc[t][3];
            *(half4*)(Or + t * 16) = o;
        }
    }
}

// ============ fused: GEMM1 ∥ phase-A coarse binning (r10-proven) ============

__launch_bounds__(256)
__global__ void k_fused1(const int* __restrict__ src, const int* __restrict__ dst,
                         int* __restrict__ coarseCnt, uint2* __restrict__ binned,
                         int E, int gblocks, int nbin,
                         const float* __restrict__ A, const _Float16* __restrict__ WT,
                         _Float16* __restrict__ Hout, int nrows) {
    __shared__ int lh[NBMAX];
    __shared__ int lb[NBMAX];
    if ((int)blockIdx.x < gblocks) {
        gemm_body<float>((int)blockIdx.x, A, WT, Hout, nrows);
        return;
    }
    const int t  = threadIdx.x;
    const int eb = ((int)blockIdx.x - gblocks) * EPB;

    for (int b = t; b < nbin; b += 256) lh[b] = 0;
    __syncthreads();

    int dv[16], sv[16], rv[16];
    #pragma unroll
    for (int k = 0; k < 16; ++k) {
        const int i = eb + k * 256 + t;
        dv[k] = -1;
        if (i < E) {
            dv[k] = dst[i];
            sv[k] = src[i];
            rv[k] = atomicAdd(&lh[dv[k] >> 7], 1);
        }
    }
    __syncthreads();

    for (int b = t; b < nbin; b += 256) {
        const int c = lh[b];
        lb[b] = (c > 0) ? atomicAdd(&coarseCnt[b], c) : 0;
    }
    __syncthreads();

    #pragma unroll
    for (int k = 0; k < 16; ++k) {
        if (dv[k] >= 0) {
            const int b   = dv[k] >> 7;
            const int pos = lb[b] + rv[k];
            if (pos < BCAP)
                binned[(size_t)b * BCAP + pos] = make_uint2((unsigned)dv[k], (unsigned)sv[k]);
        }
    }
}

// ============ k_binB: fine counting sort -> dense CSR (self-allocating) ============

__launch_bounds__(256)
__global__ void k_binB(const uint2* __restrict__ binned, const int* __restrict__ coarseCnt,
                       int* __restrict__ allocTot, int* __restrict__ epOut,
                       int* __restrict__ cnt, unsigned* __restrict__ offcnt, int n) {
    __shared__ int fh[128], pf[128];
    __shared__ int sOff;
    const int b = blockIdx.x;
    const int t = threadIdx.x;
    const int nb = min(coarseCnt[b], BCAP);
    if (t == 0) sOff = atomicAdd(allocTot, nb);

    if (t < 128) fh[t] = 0;
    __syncthreads();

    int sv_[10], fv_[10], rv_[10];
    #pragma unroll
    for (int k = 0; k < 10; ++k) {
        const int j = t + k * 256;
        fv_[k] = -1;
        if (j < nb) {
            const uint2 p = binned[(size_t)b * BCAP + j];
            fv_[k] = (int)(p.x & 127u);
            sv_[k] = (int)p.y;
            rv_[k] = atomicAdd(&fh[fv_[k]], 1);
        }
    }
    __syncthreads();

    if (t == 0) {
        int run = 0;
        for (int f = 0; f < 128; ++f) { const int c = fh[f]; pf[f] = run; run += c; }
    }
    __syncthreads();

    const int binOff = sOff;
    #pragma unroll
    for (int k = 0; k < 10; ++k)
        if (fv_[k] >= 0) epOut[binOff + pf[fv_[k]] + rv_[k]] = sv_[k];

    if (t < 128) {
        const int node = b * 128 + t;
        if (node < n) {
            const int c = fh[t];
            cnt[node]    = c;
            offcnt[node] = (unsigned)(binOff + pf[t]) | ((unsigned)min(c, 127) << 21);
        }
    }
}

// ============ k_pack: embed cnt[src] into CSR entries ============

__launch_bounds__(256)
__global__ void k_pack(int* __restrict__ epOut, const int* __restrict__ cnt,
                       const int* __restrict__ allocTot) {
    const int tot = *allocTot;
    const int i = blockIdx.x * 256 + threadIdx.x;
    if (i < tot) {
        const unsigned v = (unsigned)epOut[i];
        epOut[i] = (int)(v | ((unsigned)min(cnt[v & 0xFFFFF], 4095) << 20));
    }
}

// ============ agg row: COLUMN-PHASED quad-neighbor gathers ============
// r11 post-mortem: halving instructions was NULL -> agg is bound by the
// L2-fill path (~256 GB/s per XCD). Only lever left: reduce FETCH itself.
// Phase ph gathers only cols [ph*64, ph*64+64) of each neighbor -> hot
// footprint per phase 12.8 MB (vs 25.6) against 4 MB/XCD L2 -> higher hit
// rate, less fill. Quad layout: lanes 0-7 neighbor k, 8-15 k+1, 16-23 k+2,
// 24-31 k+3; per instruction still 4 rows x 2 lines (same coalescing as
// r11). Butterfly shfl_xor(8,16) folds the 4 subsets. Weights exact f32
// from exact packed counts -> same numerics class as all passing rounds.

template <int U>
__device__ __forceinline__ void grpq(const _Float16* __restrict__ h, int l8, int nsel,
                                     unsigned pv, float dd, int k, int m, f32x8& acc) {
    unsigned p[U]; half8 v[U];
    #pragma unroll
    for (int u = 0; u < U; ++u)
        p[u] = __shfl(pv, k + 4 * u + nsel, 32);
    #pragma unroll
    for (int u = 0; u < U; ++u)
        v[u] = *(const half8*)&h[(size_t)(p[u] & 0xFFFFFu) * D + l8];
    #pragma unroll
    for (int u = 0; u < U; ++u) {
        const float w = (k + 4 * u + nsel < m)
                      ? rsqrtf(1.0f + (float)(p[u] >> 20)) * dd : 0.0f;
        #pragma unroll
        for (int j = 0; j < 8; ++j)
            acc[j] = fmaf((float)v[u][j], w, acc[j]);
    }
}

// Returns, on ALL lanes, the aggregated 8 columns at (lane&7)*8 + ph*64.
__device__ __forceinline__ f32x8 agg_row8q(const _Float16* __restrict__ h,
                                           const unsigned* __restrict__ offcnt,
                                           const unsigned* __restrict__ ep,
                                           int row, int lane, int ph) {
    const int l8   = (lane & 7) * 8 + ph * 64;
    const int nsel = lane >> 3;          // 0..3: neighbor sub-slot
    const unsigned oc = offcnt[row];
    const int base = (int)(oc & 0x1FFFFFu);
    const int cr   = (int)((oc >> 21) & 0x7Fu);
    const float dd = rsqrtf(1.0f + (float)cr);
    const float sw = dd * dd;
    f32x8 acc = (f32x8)0.0f;

    for (int c = 0; c < cr; c += 32) {
        unsigned pv = 0;
        if (c + lane < cr) pv = ep[base + c + lane];
        const int m = min(32, cr - c);
        int k = 0;
        for (; k + 16 <= m; k += 16) grpq<4>(h, l8, nsel, pv, dd, k, m, acc);
        for (; k < m; k += 4)        grpq<1>(h, l8, nsel, pv, dd, k, m, acc);
    }

    // fold the 4 neighbor subsets (bits 3,4 of lane)
    #pragma unroll
    for (int j = 0; j < 8; ++j) {
        acc[j] += __shfl_xor(acc[j], 8, 32);
        acc[j] += __shfl_xor(acc[j], 16, 32);
    }

    const half8 hv = *(const half8*)&h[(size_t)row * D + l8];
    #pragma unroll
    for (int j = 0; j < 8; ++j) acc[j] = fmaf((float)hv[j], sw, acc[j]);
    return acc;
}

// ============ fused agg(layer1) + GEMM2: 32 rows / 128 threads ============

#define LSTRIDE 136  // _Float16 units (272 B row stride, 16B-aligned)

__launch_bounds__(128)
__global__ void k_agg_gemm2(const _Float16* __restrict__ h,
                            const unsigned* __restrict__ offcnt,
                            const unsigned* __restrict__ ep,
                            const float* __restrict__ bias, const _Float16* __restrict__ WT,
                            _Float16* __restrict__ Hout, int n) {
    __shared__ _Float16 sh[32 * LSTRIDE];

    const int r0   = blockIdx.x * 32;
    const int hw   = threadIdx.x >> 5;   // 0..3
    const int lane = threadIdx.x & 31;
    const int nsel = lane >> 3;

    #pragma unroll 1
    for (int ph = 0; ph < 2; ++ph) {
        const int l8 = (lane & 7) * 8 + ph * 64;
        const float4 bb0 = *(const float4*)&bias[l8];
        const float4 bb1 = *(const float4*)&bias[l8 + 4];
        #pragma unroll 1
        for (int i = 0; i < 8; ++i) {
            const int rl  = hw * 8 + i;
            const int row = r0 + rl;
            half8 o;
            if (row < n) {
                f32x8 a = agg_row8q(h, offcnt, ep, row, lane, ph);
                o[0] = (_Float16)fmaxf(a[0] + bb0.x, 0.f);
                o[1] = (_Float16)fmaxf(a[1] + bb0.y, 0.f);
                o[2] = (_Float16)fmaxf(a[2] + bb0.z, 0.f);
                o[3] = (_Float16)fmaxf(a[3] + bb0.w, 0.f);
                o[4] = (_Float16)fmaxf(a[4] + bb1.x, 0.f);
                o[5] = (_Float16)fmaxf(a[5] + bb1.y, 0.f);
                o[6] = (_Float16)fmaxf(a[6] + bb1.z, 0.f);
                o[7] = (_Float16)fmaxf(a[7] + bb1.w, 0.f);
            } else {
                #pragma unroll
                for (int j = 0; j < 8; ++j) o[j] = (_Float16)0.f;
            }
            if (nsel == 0) *(half8*)&sh[rl * LSTRIDE + l8] = o;
        }
    }
    __syncthreads();

    const int wv   = threadIdx.x >> 6;   // 0..1
    const int wl64 = threadIdx.x & 63;
    const int l    = wl64 & 15;
    const int quad = wl64 >> 4;
    const int rl   = wv * 16 + l;
    const int row  = r0 + rl;

    half8 af[4];
    #pragma unroll
    for (int s = 0; s < 4; ++s)
        af[s] = *(const half8*)&sh[rl * LSTRIDE + s * 32 + quad * 8];

    f32x4 acc[8];
    #pragma unroll
    for (int t = 0; t < 8; ++t) acc[t] = (f32x4)0.0f;

    #pragma unroll
    for (int s = 0; s < 4; ++s) {
        #pragma unroll
        for (int t = 0; t < 8; ++t) {
            const half8 wf = *(const half8*)&WT[(size_t)(t * 16 + l) * D + s * 32 + quad * 8];
            acc[t] = __builtin_amdgcn_mfma_f32_16x16x32_f16(wf, af[s], acc[t], 0, 0, 0);
        }
    }

    if (row < n) {
        _Float16* Or = &Hout[(size_t)row * D + quad * 4];
        #pragma unroll
        for (int t = 0; t < 8; ++t) {
            half4 o;
            o[0] = (_Float16)acc[t][0]; o[1] = (_Float16)acc[t][1];
            o[2] = (_Float16)acc[t][2]; o[3] = (_Float16)acc[t][3];
            *(half4*)(Or + t * 16) = o;
        }
    }
}

// ============ final agg (layer2) -> fp32 d_out: 8 rows / 256 thr ============

__launch_bounds__(256)
__global__ void k_agg_out(const _Float16* __restrict__ h,
                          const unsigned* __restrict__ offcnt,
                          const unsigned* __restrict__ ep,
                          const float* __restrict__ bias, float* __restrict__ out, int n) {
    const int row = blockIdx.x * 8 + (threadIdx.x >> 5);
    if (row >= n) return;
    const int lane = threadIdx.x & 31;
    const int nsel = lane >> 3;

    #pragma unroll 1
    for (int ph = 0; ph < 2; ++ph) {
        const int l8 = (lane & 7) * 8 + ph * 64;
        const float4 bb0 = *(const float4*)&bias[l8];
        const float4 bb1 = *(const float4*)&bias[l8 + 4];
        f32x8 a = agg_row8q(h, offcnt, ep, row, lane, ph);
        if (nsel == 0) {
            float4 o0 = make_float4(fmaxf(a[0] + bb0.x, 0.f), fmaxf(a[1] + bb0.y, 0.f),
                                    fmaxf(a[2] + bb0.z, 0.f), fmaxf(a[3] + bb0.w, 0.f));
            float4 o1 = make_float4(fmaxf(a[4] + bb1.x, 0.f), fmaxf(a[5] + bb1.y, 0.f),
                                    fmaxf(a[6] + bb1.z, 0.f), fmaxf(a[7] + bb1.w, 0.f));
            *(float4*)&out[(size_t)row * D + l8]     = o0;
            *(float4*)&out[(size_t)row * D + l8 + 4] = o1;
        }
    }
}

// ================= launch =================

extern "C" void kernel_launch(void* const* d_in, const int* in_sizes, int n_in,
                              void* d_out, int out_size, void* d_ws, size_t ws_size,
                              hipStream_t stream) {
    const float* x  = (const float*)d_in[0];
    const int*   ei = (const int*)d_in[1];
    const float* W1 = (const float*)d_in[2];
    const float* b1 = (const float*)d_in[3];
    const float* W2 = (const float*)d_in[4];
    const float* b2 = (const float*)d_in[5];

    const int N = in_sizes[0] / D;     // 100000
    const int E = in_sizes[1] / 2;     // 1600000
    const int* src = ei;
    const int* dst = ei + E;
    float* out = (float*)d_out;

    const int nbin = (N + 127) / 128;  // 782 (<= NBMAX)

    auto align256 = [](size_t v) { return (v + 255) & ~(size_t)255; };
    char* w = (char*)d_ws;
    int*      cnt       = (int*)w;      w += align256((size_t)N * 4);
    unsigned* offcnt    = (unsigned*)w; w += align256((size_t)N * 4);
    int*      coarseCnt = (int*)w;      w += align256((size_t)(nbin + 1) * 4);
    int*      allocTot  = coarseCnt + nbin;   // one extra int, memset together
    _Float16* WT1       = (_Float16*)w; w += align256((size_t)D * D * 2);
    _Float16* WT2       = (_Float16*)w; w += align256((size_t)D * D * 2);
    uint2*    binned    = (uint2*)w;    w += align256((size_t)nbin * BCAP * 8); // 16.0 MB
    int*      epOut     = (int*)w;      w += align256((size_t)E * 4);           // 6.4 MB
    _Float16* hA        = (_Float16*)w; w += align256((size_t)N * D * 2);       // 25.6 MB
    _Float16* hB        = (_Float16*)w;
    // total ~74.5 MB — under the proven 77 MB footprint

    const int abgrid = (E + EPB - 1) / EPB;   // 391 phase-A blocks
    const int ggrid  = (N + 63) / 64;         // 1563 GEMM blocks

    hipMemsetAsync(coarseCnt, 0, (size_t)(nbin + 1) * 4, stream);
    k_prepW2<<<(2 * D * D + 255) / 256, 256, 0, stream>>>(W1, W2, WT1, WT2);

    // GEMM1 (-> fp16 hA) first; coarse binning trickles in behind (overlap)
    k_fused1<<<ggrid + abgrid, 256, 0, stream>>>(src, dst, coarseCnt, binned, E, ggrid,
                                                 nbin, x, WT1, hA, N);

    // fine counting sort per bin -> dense CSR + cnt + offcnt (self-allocating)
    k_binB<<<nbin, 256, 0, stream>>>(binned, coarseCnt, allocTot, epOut, cnt, offcnt, N);

    // embed cnt[src] into CSR entries
    k_pack<<<(E + 255) / 256, 256, 0, stream>>>(epOut, cnt, allocTot);

    // agg(layer1) + GEMM2 fused, 32 rows/block, column-phased quad gathers
    k_agg_gemm2<<<(N + 31) / 32, 128, 0, stream>>>(hA, offcnt, (const unsigned*)epOut,
                                                   b1, WT2, hB, N);

    // final aggregation -> d_out, column-phased quad gathers
    k_agg_out<<<(N + 7) / 8, 256, 0, stream>>>(hB, offcnt, (const unsigned*)epOut,
                                               b2, out, N);
}

// Round 14
// 369.869 us; speedup vs baseline: 1.0251x; 1.0251x over previous
//
#include <hip/hip_runtime.h>
#include <hip/hip_bf16.h>
#include <hip/hip_fp16.h>

#define D 128
#define EPB 4096      // edges per phase-A block (256 thr x 16)
#define NBMAX 784     // max coarse bins (ceil(100000/128)=782)
#define BCAP 2560     // per-coarse-bin capacity: Poisson(2048) + 11 sigma

typedef _Float16 half8 __attribute__((ext_vector_type(8)));
typedef _Float16 half4 __attribute__((ext_vector_type(4)));
typedef float f32x4 __attribute__((ext_vector_type(4)));
typedef float f32x8 __attribute__((ext_vector_type(8)));
typedef unsigned u32x2 __attribute__((ext_vector_type(2)));

// ============ W prep + control memset (fused: one fewer launch) ============

__global__ void k_prepW2(const float* __restrict__ W1, const float* __restrict__ W2,
                         _Float16* __restrict__ WT1, _Float16* __restrict__ WT2,
                         int* __restrict__ coarseCnt, int nzero) {
    if (blockIdx.x == 0) {
        for (int b = threadIdx.x; b < nzero; b += 256) coarseCnt[b] = 0;
    }
    const int i = blockIdx.x * 256 + threadIdx.x;
    if (i < 2 * D * D) {
        const float* W = (i < D * D) ? W1 : W2;
        _Float16* WT   = (i < D * D) ? WT1 : WT2;
        const int j = (i < D * D) ? i : i - D * D;
        const int k = j >> 7, n = j & 127;
        WT[n * D + k] = (_Float16)W[j];
    }
}

// ============ GEMM body (A from global, nt loads: x is single-use), fp16 out ============

template <typename AT>
__device__ __forceinline__ void gemm_body(int bid, const AT* __restrict__ A,
                                          const _Float16* __restrict__ WT,
                                          _Float16* __restrict__ Hout, int nrows) {
    const int wv   = threadIdx.x >> 6;
    const int lane = threadIdx.x & 63;
    const int l    = lane & 15;
    const int quad = lane >> 4;
    const int base = bid * 64 + wv * 16;
    int row = base + l;
    const bool valid = row < nrows;
    if (!valid) row = nrows - 1;

    half8 af[4];
    const AT* Ar = &A[(size_t)row * D + quad * 8];
    #pragma unroll
    for (int s = 0; s < 4; ++s) {
        if constexpr (sizeof(AT) == 4) {
            const f32x4 v0 = __builtin_nontemporal_load((const f32x4*)(Ar + s * 32));
            const f32x4 v1 = __builtin_nontemporal_load((const f32x4*)(Ar + s * 32 + 4));
            af[s][0] = (_Float16)v0[0]; af[s][1] = (_Float16)v0[1];
            af[s][2] = (_Float16)v0[2]; af[s][3] = (_Float16)v0[3];
            af[s][4] = (_Float16)v1[0]; af[s][5] = (_Float16)v1[1];
            af[s][6] = (_Float16)v1[2]; af[s][7] = (_Float16)v1[3];
        } else {
            af[s] = *(const half8*)(Ar + s * 32);
        }
    }

    f32x4 acc[8];
    #pragma unroll
    for (int t = 0; t < 8; ++t) acc[t] = (f32x4)0.0f;

    #pragma unroll
    for (int s = 0; s < 4; ++s) {
        #pragma unroll
        for (int t = 0; t < 8; ++t) {
            const half8 wf = *(const half8*)&WT[(size_t)(t * 16 + l) * D + s * 32 + quad * 8];
            acc[t] = __builtin_amdgcn_mfma_f32_16x16x32_f16(wf, af[s], acc[t], 0, 0, 0);
        }
    }

    if (valid) {
        _Float16* Or = &Hout[(size_t)row * D + quad * 4];
        #pragma unroll
        for (int t = 0; t < 8; ++t) {
            half4 o;
            o[0] = (_Float16)acc[t][0]; o[1] = (_Float16)acc[t][1];
            o[2] = (_Float16)acc[t][2]; o[3] = (_Float16)acc[t][3];
            *(half4*)(Or + t * 16) = o;
        }
    }
}

// ============ fused: GEMM1 ∥ phase-A coarse binning (r10-proven, nt streams) ============

__launch_bounds__(256)
__global__ void k_fused1(const int* __restrict__ src, const int* __restrict__ dst,
                         int* __restrict__ coarseCnt, u32x2* __restrict__ binned,
                         int E, int gblocks, int nbin,
                         const float* __restrict__ A, const _Float16* __restrict__ WT,
                         _Float16* __restrict__ Hout, int nrows) {
    __shared__ int lh[NBMAX];
    __shared__ int lb[NBMAX];
    if ((int)blockIdx.x < gblocks) {
        gemm_body<float>((int)blockIdx.x, A, WT, Hout, nrows);
        return;
    }
    const int t  = threadIdx.x;
    const int eb = ((int)blockIdx.x - gblocks) * EPB;

    for (int b = t; b < nbin; b += 256) lh[b] = 0;
    __syncthreads();

    int dv[16], sv[16], rv[16];
    #pragma unroll
    for (int k = 0; k < 16; ++k) {
        const int i = eb + k * 256 + t;
        dv[k] = -1;
        if (i < E) {
            dv[k] = __builtin_nontemporal_load(dst + i);
            sv[k] = __builtin_nontemporal_load(src + i);
            rv[k] = atomicAdd(&lh[dv[k] >> 7], 1);
        }
    }
    __syncthreads();

    for (int b = t; b < nbin; b += 256) {
        const int c = lh[b];
        lb[b] = (c > 0) ? atomicAdd(&coarseCnt[b], c) : 0;
    }
    __syncthreads();

    #pragma unroll
    for (int k = 0; k < 16; ++k) {
        if (dv[k] >= 0) {
            const int b   = dv[k] >> 7;
            const int pos = lb[b] + rv[k];
            if (pos < BCAP) {
                u32x2 pr; pr[0] = (unsigned)dv[k]; pr[1] = (unsigned)sv[k];
                __builtin_nontemporal_store(pr, &binned[(size_t)b * BCAP + pos]);
            }
        }
    }
}

// ============ k_binB: fine counting sort -> dense CSR (self-allocating) ============

__launch_bounds__(256)
__global__ void k_binB(const u32x2* __restrict__ binned, const int* __restrict__ coarseCnt,
                       int* __restrict__ allocTot, int* __restrict__ epOut,
                       int* __restrict__ cnt, unsigned* __restrict__ offcnt, int n) {
    __shared__ int fh[128], pf[128];
    __shared__ int sOff;
    const int b = blockIdx.x;
    const int t = threadIdx.x;
    const int nb = min(coarseCnt[b], BCAP);
    if (t == 0) sOff = atomicAdd(allocTot, nb);

    if (t < 128) fh[t] = 0;
    __syncthreads();

    int sv_[10], fv_[10], rv_[10];
    #pragma unroll
    for (int k = 0; k < 10; ++k) {
        const int j = t + k * 256;
        fv_[k] = -1;
        if (j < nb) {
            const u32x2 p = __builtin_nontemporal_load(&binned[(size_t)b * BCAP + j]);
            fv_[k] = (int)(p[0] & 127u);
            sv_[k] = (int)p[1];
            rv_[k] = atomicAdd(&fh[fv_[k]], 1);
        }
    }
    __syncthreads();

    if (t == 0) {
        int run = 0;
        for (int f = 0; f < 128; ++f) { const int c = fh[f]; pf[f] = run; run += c; }
    }
    __syncthreads();

    const int binOff = sOff;
    #pragma unroll
    for (int k = 0; k < 10; ++k)
        if (fv_[k] >= 0) epOut[binOff + pf[fv_[k]] + rv_[k]] = sv_[k];

    if (t < 128) {
        const int node = b * 128 + t;
        if (node < n) {
            const int c = fh[t];
            cnt[node]    = c;
            offcnt[node] = (unsigned)(binOff + pf[t]) | ((unsigned)min(c, 127) << 21);
        }
    }
}

// ============ k_pack: embed cnt[src] into CSR entries ============

__launch_bounds__(256)
__global__ void k_pack(int* __restrict__ epOut, const int* __restrict__ cnt,
                       const int* __restrict__ allocTot) {
    const int tot = *allocTot;
    const int i = blockIdx.x * 256 + threadIdx.x;
    if (i < tot) {
        const unsigned v = (unsigned)epOut[i];
        epOut[i] = (int)(v | ((unsigned)min(cnt[v & 0xFFFFF], 4095) << 20));
    }
}

// ============ agg row: DUAL-NEIGHBOR half8 gathers (r11-proven; nt ep loads) ============
// r11/r12 synthesis: agg is at ~2 TB/s on the L2-fill path; instruction count
// (r11) and footprint (r12) are not the lever. ep/offcnt are single-use
// streams -> nt loads keep L2 for the reused h-row gathers.

template <int U>
__device__ __forceinline__ void grp2(const _Float16* __restrict__ h, int l8, int hh,
                                     unsigned pv, float dd, int k, int m, f32x8& acc) {
    unsigned p[U]; half8 v[U];
    #pragma unroll
    for (int u = 0; u < U; ++u)
        p[u] = __shfl(pv, k + 2 * u + hh, 32);
    #pragma unroll
    for (int u = 0; u < U; ++u)
        v[u] = *(const half8*)&h[(size_t)(p[u] & 0xFFFFFu) * D + l8];
    #pragma unroll
    for (int u = 0; u < U; ++u) {
        const float w = (k + 2 * u + hh < m)
                      ? rsqrtf(1.0f + (float)(p[u] >> 20)) * dd : 0.0f;
        #pragma unroll
        for (int j = 0; j < 8; ++j)
            acc[j] = fmaf((float)v[u][j], w, acc[j]);
    }
}

__device__ __forceinline__ f32x8 agg_row8(const _Float16* __restrict__ h,
                                          const unsigned* __restrict__ offcnt,
                                          const unsigned* __restrict__ ep,
                                          int row, int lane) {
    const int l8 = (lane & 15) * 8;
    const int hh = lane >> 4;            // 0: even neighbors, 1: odd neighbors
    const unsigned oc = offcnt[row];
    const int base = (int)(oc & 0x1FFFFFu);
    const int cr   = (int)((oc >> 21) & 0x7Fu);
    const float dd = rsqrtf(1.0f + (float)cr);
    const float sw = dd * dd;
    f32x8 acc = (f32x8)0.0f;

    for (int c = 0; c < cr; c += 32) {
        unsigned pv = 0;
        if (c + lane < cr) pv = __builtin_nontemporal_load(ep + base + c + lane);
        const int m = min(32, cr - c);
        int k = 0;
        for (; k + 8 <= m; k += 8) grp2<4>(h, l8, hh, pv, dd, k, m, acc);
        for (; k < m; k += 2)      grp2<1>(h, l8, hh, pv, dd, k, m, acc);
    }

    #pragma unroll
    for (int j = 0; j < 8; ++j) acc[j] += __shfl_xor(acc[j], 16, 32);

    const half8 hv = *(const half8*)&h[(size_t)row * D + l8];
    #pragma unroll
    for (int j = 0; j < 8; ++j) acc[j] = fmaf((float)hv[j], sw, acc[j]);
    return acc;
}

// ============ fused agg(layer1) + GEMM2: 32 rows / 128 threads ============

#define LSTRIDE 136  // _Float16 units (272 B row stride, 16B-aligned)

__launch_bounds__(128)
__global__ void k_agg_gemm2(const _Float16* __restrict__ h,
                            const unsigned* __restrict__ offcnt,
                            const unsigned* __restrict__ ep,
                            const float* __restrict__ bias, const _Float16* __restrict__ WT,
                            _Float16* __restrict__ Hout, int n) {
    __shared__ _Float16 sh[32 * LSTRIDE];

    const int r0   = blockIdx.x * 32;
    const int hw   = threadIdx.x >> 5;   // 0..3
    const int lane = threadIdx.x & 31;
    const int l8   = (lane & 15) * 8;
    const int hh   = lane >> 4;
    const float4 bb0 = *(const float4*)&bias[l8];
    const float4 bb1 = *(const float4*)&bias[l8 + 4];

    #pragma unroll 1
    for (int i = 0; i < 8; ++i) {
        const int rl  = hw * 8 + i;
        const int row = r0 + rl;
        half8 o;
        if (row < n) {
            f32x8 a = agg_row8(h, offcnt, ep, row, lane);
            o[0] = (_Float16)fmaxf(a[0] + bb0.x, 0.f);
            o[1] = (_Float16)fmaxf(a[1] + bb0.y, 0.f);
            o[2] = (_Float16)fmaxf(a[2] + bb0.z, 0.f);
            o[3] = (_Float16)fmaxf(a[3] + bb0.w, 0.f);
            o[4] = (_Float16)fmaxf(a[4] + bb1.x, 0.f);
            o[5] = (_Float16)fmaxf(a[5] + bb1.y, 0.f);
            o[6] = (_Float16)fmaxf(a[6] + bb1.z, 0.f);
            o[7] = (_Float16)fmaxf(a[7] + bb1.w, 0.f);
        } else {
            #pragma unroll
            for (int j = 0; j < 8; ++j) o[j] = (_Float16)0.f;
        }
        if (hh == 0) *(half8*)&sh[rl * LSTRIDE + l8] = o;
    }
    __syncthreads();

    const int wv   = threadIdx.x >> 6;   // 0..1
    const int wl64 = threadIdx.x & 63;
    const int l    = wl64 & 15;
    const int quad = wl64 >> 4;
    const int rl   = wv * 16 + l;
    const int row  = r0 + rl;

    half8 af[4];
    #pragma unroll
    for (int s = 0; s < 4; ++s)
        af[s] = *(const half8*)&sh[rl * LSTRIDE + s * 32 + quad * 8];

    f32x4 acc[8];
    #pragma unroll
    for (int t = 0; t < 8; ++t) acc[t] = (f32x4)0.0f;

    #pragma unroll
    for (int s = 0; s < 4; ++s) {
        #pragma unroll
        for (int t = 0; t < 8; ++t) {
            const half8 wf = *(const half8*)&WT[(size_t)(t * 16 + l) * D + s * 32 + quad * 8];
            acc[t] = __builtin_amdgcn_mfma_f32_16x16x32_f16(wf, af[s], acc[t], 0, 0, 0);
        }
    }

    if (row < n) {
        _Float16* Or = &Hout[(size_t)row * D + quad * 4];
        #pragma unroll
        for (int t = 0; t < 8; ++t) {
            half4 o;
            o[0] = (_Float16)acc[t][0]; o[1] = (_Float16)acc[t][1];
            o[2] = (_Float16)acc[t][2]; o[3] = (_Float16)acc[t][3];
            *(half4*)(Or + t * 16) = o;
        }
    }
}

// ============ final agg (layer2) -> fp32 d_out (nt stores: out is write-once) ============

__launch_bounds__(256)
__global__ void k_agg_out(const _Float16* __restrict__ h,
                          const unsigned* __restrict__ offcnt,
                          const unsigned* __restrict__ ep,
                          const float* __restrict__ bias, float* __restrict__ out, int n) {
    const int row = blockIdx.x * 8 + (threadIdx.x >> 5);
    if (row >= n) return;
    const int lane = threadIdx.x & 31;
    const int l8   = (lane & 15) * 8;
    const int hh   = lane >> 4;
    const float4 bb0 = *(const float4*)&bias[l8];
    const float4 bb1 = *(const float4*)&bias[l8 + 4];

    f32x8 a = agg_row8(h, offcnt, ep, row, lane);
    if (hh == 0) {
        f32x4 o0, o1;
        o0[0] = fmaxf(a[0] + bb0.x, 0.f); o0[1] = fmaxf(a[1] + bb0.y, 0.f);
        o0[2] = fmaxf(a[2] + bb0.z, 0.f); o0[3] = fmaxf(a[3] + bb0.w, 0.f);
        o1[0] = fmaxf(a[4] + bb1.x, 0.f); o1[1] = fmaxf(a[5] + bb1.y, 0.f);
        o1[2] = fmaxf(a[6] + bb1.z, 0.f); o1[3] = fmaxf(a[7] + bb1.w, 0.f);
        __builtin_nontemporal_store(o0, (f32x4*)&out[(size_t)row * D + l8]);
        __builtin_nontemporal_store(o1, (f32x4*)&out[(size_t)row * D + l8 + 4]);
    }
}

// ================= launch =================

extern "C" void kernel_launch(void* const* d_in, const int* in_sizes, int n_in,
                              void* d_out, int out_size, void* d_ws, size_t ws_size,
                              hipStream_t stream) {
    const float* x  = (const float*)d_in[0];
    const int*   ei = (const int*)d_in[1];
    const float* W1 = (const float*)d_in[2];
    const float* b1 = (const float*)d_in[3];
    const float* W2 = (const float*)d_in[4];
    const float* b2 = (const float*)d_in[5];

    const int N = in_sizes[0] / D;     // 100000
    const int E = in_sizes[1] / 2;     // 1600000
    const int* src = ei;
    const int* dst = ei + E;
    float* out = (float*)d_out;

    const int nbin = (N + 127) / 128;  // 782 (<= NBMAX)

    auto align256 = [](size_t v) { return (v + 255) & ~(size_t)255; };
    char* w = (char*)d_ws;
    int*      cnt       = (int*)w;      w += align256((size_t)N * 4);
    unsigned* offcnt    = (unsigned*)w; w += align256((size_t)N * 4);
    int*      coarseCnt = (int*)w;      w += align256((size_t)(nbin + 1) * 4);
    int*      allocTot  = coarseCnt + nbin;   // one extra int, zeroed with coarseCnt
    _Float16* WT1       = (_Float16*)w; w += align256((size_t)D * D * 2);
    _Float16* WT2       = (_Float16*)w; w += align256((size_t)D * D * 2);
    u32x2*    binned    = (u32x2*)w;    w += align256((size_t)nbin * BCAP * 8); // 16.0 MB
    int*      epOut     = (int*)w;      w += align256((size_t)E * 4);           // 6.4 MB
    _Float16* hA        = (_Float16*)w; w += align256((size_t)N * D * 2);       // 25.6 MB
    _Float16* hB        = (_Float16*)w;
    // total ~74.5 MB — under the proven 77 MB footprint

    const int abgrid = (E + EPB - 1) / EPB;   // 391 phase-A blocks
    const int ggrid  = (N + 63) / 64;         // 1563 GEMM blocks

    // W transpose + control-array zeroing fused (no separate memset launch)
    k_prepW2<<<(2 * D * D + 255) / 256, 256, 0, stream>>>(W1, W2, WT1, WT2,
                                                          coarseCnt, nbin + 1);

    // GEMM1 (-> fp16 hA) first; coarse binning trickles in behind (overlap)
    k_fused1<<<ggrid + abgrid, 256, 0, stream>>>(src, dst, coarseCnt, binned, E, ggrid,
                                                 nbin, x, WT1, hA, N);

    // fine counting sort per bin -> dense CSR + cnt + offcnt (self-allocating)
    k_binB<<<nbin, 256, 0, stream>>>(binned, coarseCnt, allocTot, epOut, cnt, offcnt, N);

    // embed cnt[src] into CSR entries
    k_pack<<<(E + 255) / 256, 256, 0, stream>>>(epOut, cnt, allocTot);

    // agg(layer1) + GEMM2 fused, 32 rows/block, dual-neighbor gathers
    k_agg_gemm2<<<(N + 31) / 32, 128, 0, stream>>>(hA, offcnt, (const unsigned*)epOut,
                                                   b1, WT2, hB, N);

    // final aggregation -> d_out, dual-neighbor gathers, nt output stores
    k_agg_out<<<(N + 7) / 8, 256, 0, stream>>>(hB, offcnt, (const unsigned*)epOut,
                                               b2, out, N);
}